// Round 5
// baseline (934.652 us; speedup 1.0000x reference)
//
#include <hip/hip_runtime.h>

// Problem constants: N=50000, D=64, R=3, E=800000
#define N_NODES 50000
#define DFEAT   64
#define NREL    3
#define NEDGE   800000
#define OUT_COLS 256                 // (R+1)*D floats per output row
#define BROWS   128                  // rows per bucket
#define NBUCK   ((N_NODES + BROWS - 1) / BROWS)   // 391
#define TB      (NREL * NBUCK)       // 1173
#define SCAT_BLOCKS 200
#define SRTCAP  2432                 // sorted-record LDS capacity (mean 2048, +8.5 sigma)
#define WIN_SHIFT 11                 // col window = col>>11 (2048 cols)
#define NWIN    32                   // >= ceil(50000/2048)=25

static __device__ inline unsigned short f2bf(float f) {
    unsigned u = __float_as_uint(f);
    unsigned r = u + 0x7FFFu + ((u >> 16) & 1u);   // round-to-nearest-even
    return (unsigned short)(r >> 16);
}
static __device__ inline float bf2f(unsigned short h) {
    return __uint_as_float(((unsigned)h) << 16);
}

// ---------------- bucketed path ----------------

__global__ void zero_counts_kernel(int* __restrict__ counts) {
    int i = blockIdx.x * 256 + threadIdx.x;
    if (i < TB) counts[i] = 0;
}

// x (f32) -> xb (bf16), streaming
__global__ void cvt_kernel(const float4* __restrict__ x4, ushort4* __restrict__ xb4) {
    int i = blockIdx.x * 256 + threadIdx.x;
    if (i >= N_NODES * DFEAT / 4) return;
    float4 v = x4[i];
    ushort4 o;
    o.x = f2bf(v.x); o.y = f2bf(v.y); o.z = f2bf(v.z); o.w = f2bf(v.w);
    xb4[i] = o;
}

// grid (128, NREL), block 256. LDS histogram per block, flush with atomics.
__global__ void count_kernel(const int* __restrict__ rows, int* __restrict__ counts) {
    __shared__ int hist[NBUCK];
    int rel = blockIdx.y;
    int tid = threadIdx.x;
    for (int i = tid; i < NBUCK; i += 256) hist[i] = 0;
    __syncthreads();
    const int* rr = rows + rel * NEDGE;
    for (int e = blockIdx.x * 256 + tid; e < NEDGE; e += gridDim.x * 256)
        atomicAdd(&hist[rr[e] >> 7], 1);
    __syncthreads();
    for (int i = tid; i < NBUCK; i += 256)
        if (hist[i]) atomicAdd(&counts[rel * NBUCK + i], hist[i]);
}

// single block of 256. counts[TB] -> offsets[TB+1]; cursor = copy of offsets.
__global__ void scan_kernel(const int* __restrict__ counts,
                            int* __restrict__ offsets,
                            int* __restrict__ cursor) {
    __shared__ int part[256];
    const int PER = (TB + 255) / 256;   // 5
    int t = threadIdx.x;
    int base = t * PER;
    int loc[PER];
    int s = 0;
    for (int k = 0; k < PER; ++k) {
        int idx = base + k;
        int v = (idx < TB) ? counts[idx] : 0;
        loc[k] = s;
        s += v;
    }
    part[t] = s;
    __syncthreads();
    for (int off = 1; off < 256; off <<= 1) {
        int v = 0;
        if (t >= off) v = part[t - off];
        __syncthreads();
        if (t >= off) part[t] += v;
        __syncthreads();
    }
    int excl = (t == 0) ? 0 : part[t - 1];
    for (int k = 0; k < PER; ++k) {
        int idx = base + k;
        if (idx < TB) {
            int v = excl + loc[k];
            offsets[idx] = v;
            cursor[idx]  = v;
        }
    }
    if (t == 255) offsets[TB] = part[255];
}

// grid (SCAT_BLOCKS, NREL), block 256. Two-pass block reservation, then scatter
// packed records {(col<<7)|rowlocal, val_bits} into bucket-contiguous ws.
__global__ void scatter_kernel(const int* __restrict__ rows,
                               const int* __restrict__ cols,
                               const float* __restrict__ vals,
                               int* __restrict__ cursor,
                               uint2* __restrict__ recs) {
    __shared__ int hist[NBUCK];
    __shared__ int basei[NBUCK];
    int rel = blockIdx.y;
    int tid = threadIdx.x;
    for (int i = tid; i < NBUCK; i += 256) hist[i] = 0;
    __syncthreads();
    const int*   rr = rows + rel * NEDGE;
    const int*   cc = cols + rel * NEDGE;
    const float* vv = vals + rel * NEDGE;
    const int chunk = (NEDGE + gridDim.x - 1) / gridDim.x;
    int e0 = blockIdx.x * chunk;
    int e1 = min(e0 + chunk, NEDGE);
    for (int e = e0 + tid; e < e1; e += 256)
        atomicAdd(&hist[rr[e] >> 7], 1);
    __syncthreads();
    for (int i = tid; i < NBUCK; i += 256) {
        int c = hist[i];
        basei[i] = (c > 0) ? atomicAdd(&cursor[rel * NBUCK + i], c) : 0;
        hist[i] = 0;
    }
    __syncthreads();
    for (int e = e0 + tid; e < e1; e += 256) {
        int row = rr[e];
        int bk = row >> 7;
        int pos = basei[bk] + atomicAdd(&hist[bk], 1);
        recs[pos] = make_uint2(((unsigned)cc[e] << 7) | (unsigned)(row & 127),
                               __float_as_uint(vv[e]));
    }
}

// grid TB blocks, block 512 (8 waves). Counting-sort the WHOLE bucket's
// records by column window (col>>11) into LDS, then replay in window order:
// every block sweeps x monotonically window-by-window, so the chip-wide
// instantaneous x working set is a few windows (~0.5 MB bf16) -> L2-hit
// gathers. Gather is bf16 (128B/record = 2 cache lines, half of f32).
template <bool BF16>
__global__ void accum_kernel(const void* __restrict__ xsrc,
                             const int* __restrict__ offsets,
                             const uint2* __restrict__ recs,
                             float* __restrict__ out) {
    __shared__ float acc[BROWS * DFEAT];     // 32 KB
    __shared__ uint2 srt[SRTCAP];            // 19 KB
    __shared__ int bins[NWIN];
    __shared__ int binoff[NWIN];

    int b    = blockIdx.x;
    int rel  = b / NBUCK;
    int buck = b % NBUCK;
    int tid  = threadIdx.x;
    int lane = tid & 63, wave = tid >> 6;

    float4* acc4 = (float4*)acc;
    for (int i = tid; i < BROWS * DFEAT / 4; i += 512)
        acc4[i] = make_float4(0.f, 0.f, 0.f, 0.f);
    if (tid < NWIN) bins[tid] = 0;

    int start = offsets[b], end = offsets[b + 1];
    int total = end - start;
    int cap   = min(total, SRTCAP);
    __syncthreads();

    // pass 1: window histogram (stream recs from global)
    for (int i = start + tid; i < end; i += 512)
        atomicAdd(&bins[recs[i].x >> (7 + WIN_SHIFT)], 1);
    __syncthreads();
    if (tid == 0) {
        int s = 0;
        for (int k = 0; k < NWIN; ++k) { binoff[k] = s; s += bins[k]; bins[k] = binoff[k]; }
    }
    __syncthreads();
    // pass 2: scatter into window-sorted LDS copy
    for (int i = start + tid; i < end; i += 512) {
        uint2 r = recs[i];
        int pos = atomicAdd(&bins[r.x >> (7 + WIN_SHIFT)], 1);
        if (pos < SRTCAP) srt[pos] = r;
    }
    __syncthreads();

    // replay in window order; waves strided per-record
    const ushort* xb = (const ushort*)xsrc;
    const float*  xf = (const float*)xsrc;
    #pragma unroll 16
    for (int i = wave; i < cap; i += 8) {
        uint2 rk = srt[i];
        unsigned idx = (rk.x >> 7) * DFEAT + lane;
        float xv = BF16 ? bf2f(xb[idx]) : xf[idx];
        atomicAdd(&acc[(rk.x & 127) * DFEAT + lane],
                  __uint_as_float(rk.y) * xv);
    }
    // overflow records (statistically never): straight from global
    for (int i = cap + wave; i < total; i += 8) {
        uint2 rk = recs[start + i];
        unsigned idx = (rk.x >> 7) * DFEAT + lane;
        float xv = BF16 ? bf2f(xb[idx]) : xf[idx];
        atomicAdd(&acc[(rk.x & 127) * DFEAT + lane],
                  __uint_as_float(rk.y) * xv);
    }
    __syncthreads();

    int row0 = buck * BROWS;
    for (int i = tid; i < BROWS * DFEAT / 4; i += 512) {
        int rowl = i >> 4;     // 16 float4 per row
        int c4   = i & 15;
        int row  = row0 + rowl;
        if (row < N_NODES)
            ((float4*)out)[row * (OUT_COLS / 4) + rel * 16 + c4] = acc4[i];
    }
}

// out[:, 192:256] = x
__global__ void copyx_kernel(const float4* __restrict__ x4, float4* __restrict__ out4) {
    int i = blockIdx.x * 256 + threadIdx.x;
    if (i >= N_NODES * 16) return;
    int row = i >> 4, c = i & 15;
    out4[row * (OUT_COLS / 4) + 48 + c] = x4[i];
}

// ---------------- fallback path (no workspace) ----------------

__global__ void init_out_kernel(const float4* __restrict__ x4, float4* __restrict__ out4) {
    int j = blockIdx.x * blockDim.x + threadIdx.x;
    if (j >= N_NODES * 64) return;
    int row = j >> 6, c = j & 63;
    float4 v;
    if (c < 48) v = make_float4(0.f, 0.f, 0.f, 0.f);
    else        v = x4[row * 16 + (c - 48)];
    out4[j] = v;
}

__global__ void scatter_spmm_kernel(const float* __restrict__ x,
                                    const int* __restrict__ rows,
                                    const int* __restrict__ cols,
                                    const float* __restrict__ vals,
                                    float* __restrict__ out) {
    int idx = blockIdx.x * blockDim.x + threadIdx.x;
    int e = idx >> 4, sub = idx & 15;
    if (e >= NEDGE) return;
    int r = blockIdx.y;
    long base = (long)r * NEDGE + e;
    int row = rows[base], col = cols[base];
    float val = vals[base];
    const float4 xv = *reinterpret_cast<const float4*>(x + (long)col * DFEAT + sub * 4);
    float* o = out + (long)row * OUT_COLS + r * DFEAT + sub * 4;
    atomicAdd(o + 0, val * xv.x);
    atomicAdd(o + 1, val * xv.y);
    atomicAdd(o + 2, val * xv.z);
    atomicAdd(o + 3, val * xv.w);
}

// ---------------- launch ----------------

extern "C" void kernel_launch(void* const* d_in, const int* in_sizes, int n_in,
                              void* d_out, int out_size, void* d_ws, size_t ws_size,
                              hipStream_t stream) {
    const float* x         = (const float*)d_in[0];
    const int*   edge_rows = (const int*)d_in[1];
    const int*   edge_cols = (const int*)d_in[2];
    const float* edge_vals = (const float*)d_in[3];
    float* out = (float*)d_out;

    const size_t REC_OFF   = 32768;
    const size_t REC_BYTES = (size_t)NREL * NEDGE * sizeof(uint2);   // 19.2 MB
    const size_t XB_OFF    = REC_OFF + REC_BYTES;                    // 19,232,768
    const size_t XB_BYTES  = (size_t)N_NODES * DFEAT * sizeof(ushort); // 6.4 MB
    const size_t NEED_FULL = XB_OFF + XB_BYTES;                      // ~25.6 MB
    const size_t NEED_MIN  = REC_OFF + REC_BYTES;                    // ~19.2 MB

    if (ws_size >= NEED_MIN) {
        int*   counts  = (int*)d_ws;            // TB ints
        int*   offsets = counts + TB;           // TB+1 ints
        int*   cursor  = offsets + TB + 1;      // TB ints  (< 32 KB total)
        uint2* recs    = (uint2*)((char*)d_ws + REC_OFF);
        ushort* xb     = (ushort*)((char*)d_ws + XB_OFF);
        bool   bf16ok  = (ws_size >= NEED_FULL);

        zero_counts_kernel<<<(TB + 255) / 256, 256, 0, stream>>>(counts);
        if (bf16ok)
            cvt_kernel<<<(N_NODES * DFEAT / 4 + 255) / 256, 256, 0, stream>>>(
                (const float4*)x, (ushort4*)xb);
        count_kernel<<<dim3(128, NREL), 256, 0, stream>>>(edge_rows, counts);
        scan_kernel<<<1, 256, 0, stream>>>(counts, offsets, cursor);
        scatter_kernel<<<dim3(SCAT_BLOCKS, NREL), 256, 0, stream>>>(
            edge_rows, edge_cols, edge_vals, cursor, recs);
        if (bf16ok)
            accum_kernel<true><<<TB, 512, 0, stream>>>(xb, offsets, recs, out);
        else
            accum_kernel<false><<<TB, 512, 0, stream>>>(x, offsets, recs, out);
        copyx_kernel<<<(N_NODES * 16 + 255) / 256, 256, 0, stream>>>(
            (const float4*)x, (float4*)out);
    } else {
        // Fallback: global-atomic scatter (correct, slower)
        {
            int total = N_NODES * 64;
            init_out_kernel<<<(total + 255) / 256, 256, 0, stream>>>(
                (const float4*)x, (float4*)out);
        }
        {
            int threads_per_rel = NEDGE * 16;
            int blocks = (threads_per_rel + 255) / 256;
            dim3 grid(blocks, NREL);
            scatter_spmm_kernel<<<grid, 256, 0, stream>>>(
                x, edge_rows, edge_cols, edge_vals, out);
        }
    }
}

// Round 6
// 420.447 us; speedup vs baseline: 2.2230x; 2.2230x over previous
//
#include <hip/hip_runtime.h>

// Problem constants: N=50000, D=64, R=3, E=800000
#define N_NODES 50000
#define DFEAT   64
#define NREL    3
#define NEDGE   800000
#define OUT_COLS 256                          // (R+1)*D floats per output row
#define NBINS   (NREL * N_NODES)              // 150000 (rel-major row bins)
#define ROWBLK  128
#define NRB     ((N_NODES + ROWBLK - 1) / ROWBLK)   // 391
#define SCAN_ELEMS  1024
#define SCAN_BLOCKS ((NBINS + SCAN_ELEMS - 1) / SCAN_ELEMS)  // 147
#define EDGE_BLOCKS ((NEDGE + 255) / 256)     // 3125

// ---------------- row-sorted CSR path ----------------

__global__ void zero_counts_kernel(int* __restrict__ counts) {
    int i = blockIdx.x * 256 + threadIdx.x;
    if (i < NBINS) counts[i] = 0;
}

// grid (EDGE_BLOCKS, NREL). One global int atomic per edge into its (rel,row) bin.
__global__ void count2_kernel(const int* __restrict__ rows, int* __restrict__ counts) {
    int rel = blockIdx.y;
    int e = blockIdx.x * 256 + threadIdx.x;
    if (e >= NEDGE) return;
    atomicAdd(&counts[rel * N_NODES + rows[rel * NEDGE + e]], 1);
}

// scan stage A: per-1024-chunk totals
__global__ void scanA_kernel(const int* __restrict__ counts, int* __restrict__ partials) {
    __shared__ int red[256];
    int blk = blockIdx.x, t = threadIdx.x;
    int i0 = blk * SCAN_ELEMS + t * 4;
    int s = 0;
    #pragma unroll
    for (int k = 0; k < 4; ++k) { int i = i0 + k; if (i < NBINS) s += counts[i]; }
    red[t] = s;
    __syncthreads();
    for (int off = 128; off > 0; off >>= 1) {
        if (t < off) red[t] += red[t + off];
        __syncthreads();
    }
    if (t == 0) partials[blk] = red[0];
}

// scan stage B: exclusive scan of the 147 partials (in place)
__global__ void scanB_kernel(int* __restrict__ partials) {
    __shared__ int tmp[SCAN_BLOCKS];
    int t = threadIdx.x;
    if (t < SCAN_BLOCKS) tmp[t] = partials[t];
    __syncthreads();
    if (t == 0) {
        int s = 0;
        for (int k = 0; k < SCAN_BLOCKS; ++k) { int v = tmp[k]; tmp[k] = s; s += v; }
    }
    __syncthreads();
    if (t < SCAN_BLOCKS) partials[t] = tmp[t];
}

// scan stage C: per-chunk exclusive scan + block base -> cursor (start offsets)
__global__ void scanC_kernel(const int* __restrict__ counts,
                             const int* __restrict__ partials,
                             int* __restrict__ cursor) {
    __shared__ int part[256];
    int blk = blockIdx.x, t = threadIdx.x;
    int i0 = blk * SCAN_ELEMS + t * 4;
    int v[4];
    int s = 0;
    #pragma unroll
    for (int k = 0; k < 4; ++k) {
        int i = i0 + k;
        v[k] = (i < NBINS) ? counts[i] : 0;
        s += v[k];
    }
    part[t] = s;
    __syncthreads();
    for (int off = 1; off < 256; off <<= 1) {
        int add = (t >= off) ? part[t - off] : 0;
        __syncthreads();
        part[t] += add;
        __syncthreads();
    }
    int base = partials[blk] + ((t == 0) ? 0 : part[t - 1]);
    #pragma unroll
    for (int k = 0; k < 4; ++k) {
        int i = i0 + k;
        if (i < NBINS) cursor[i] = base;
        base += v[k];
    }
}

// grid (EDGE_BLOCKS, NREL). Scatter each edge's {col, val} into its row's
// contiguous segment. After this kernel, cursor[bin] == end offset of bin.
__global__ void scatter2_kernel(const int* __restrict__ rows,
                                const int* __restrict__ cols,
                                const float* __restrict__ vals,
                                int* __restrict__ cursor,
                                uint2* __restrict__ recs) {
    int rel = blockIdx.y;
    int e = blockIdx.x * 256 + threadIdx.x;
    if (e >= NEDGE) return;
    long src = (long)rel * NEDGE + e;
    int row = rows[src];
    int pos = atomicAdd(&cursor[rel * N_NODES + row], 1);
    recs[pos] = make_uint2((unsigned)cols[src], __float_as_uint(vals[src]));
}

// grid (NRB, NREL), block 512 (8 waves). Wave w owns rows [row0+16w, +16).
// Each row's records are contiguous; lane d accumulates out[row, rel*64+d]
// in a REGISTER (2 partial sums, unroll 4) and does ONE plain coalesced
// store per row. No LDS, no atomics.
__global__ void accum2_kernel(const float* __restrict__ x,
                              const int* __restrict__ cursor,
                              const uint2* __restrict__ recs,
                              float* __restrict__ out) {
    int rel  = blockIdx.y;
    int row0 = blockIdx.x * ROWBLK;
    int lane = threadIdx.x & 63;
    int w    = threadIdx.x >> 6;
    int rbeg = row0 + w * (ROWBLK / 8);
    if (rbeg >= N_NODES) return;
    int rend = min(rbeg + ROWBLK / 8, N_NODES);

    int bin0 = rel * N_NODES + rbeg;
    int e0 = (bin0 == 0) ? 0 : cursor[bin0 - 1];   // start of first row
    for (int row = rbeg; row < rend; ++row) {
        int e1 = cursor[rel * N_NODES + row];      // end of this row
        float s0 = 0.f, s1 = 0.f;
        int j = e0;
        for (; j + 4 <= e1; j += 4) {
            uint2 a = recs[j];
            uint2 b = recs[j + 1];
            uint2 c = recs[j + 2];
            uint2 d = recs[j + 3];
            float xa = x[(a.x << 6) + lane];
            float xb = x[(b.x << 6) + lane];
            float xc = x[(c.x << 6) + lane];
            float xd = x[(d.x << 6) + lane];
            s0 = fmaf(__uint_as_float(a.y), xa, s0);
            s1 = fmaf(__uint_as_float(b.y), xb, s1);
            s0 = fmaf(__uint_as_float(c.y), xc, s0);
            s1 = fmaf(__uint_as_float(d.y), xd, s1);
        }
        for (; j < e1; ++j) {
            uint2 a = recs[j];
            s0 = fmaf(__uint_as_float(a.y), x[(a.x << 6) + lane], s0);
        }
        out[(long)row * OUT_COLS + rel * DFEAT + lane] = s0 + s1;
        e0 = e1;
    }
}

// out[:, 192:256] = x
__global__ void copyx_kernel(const float4* __restrict__ x4, float4* __restrict__ out4) {
    int i = blockIdx.x * 256 + threadIdx.x;
    if (i >= N_NODES * 16) return;
    int row = i >> 4, c = i & 15;
    out4[row * (OUT_COLS / 4) + 48 + c] = x4[i];
}

// ---------------- fallback path (no workspace) ----------------

__global__ void init_out_kernel(const float4* __restrict__ x4, float4* __restrict__ out4) {
    int j = blockIdx.x * blockDim.x + threadIdx.x;
    if (j >= N_NODES * 64) return;
    int row = j >> 6, c = j & 63;
    float4 v;
    if (c < 48) v = make_float4(0.f, 0.f, 0.f, 0.f);
    else        v = x4[row * 16 + (c - 48)];
    out4[j] = v;
}

__global__ void scatter_spmm_kernel(const float* __restrict__ x,
                                    const int* __restrict__ rows,
                                    const int* __restrict__ cols,
                                    const float* __restrict__ vals,
                                    float* __restrict__ out) {
    int idx = blockIdx.x * blockDim.x + threadIdx.x;
    int e = idx >> 4, sub = idx & 15;
    if (e >= NEDGE) return;
    int r = blockIdx.y;
    long base = (long)r * NEDGE + e;
    int row = rows[base], col = cols[base];
    float val = vals[base];
    const float4 xv = *reinterpret_cast<const float4*>(x + (long)col * DFEAT + sub * 4);
    float* o = out + (long)row * OUT_COLS + r * DFEAT + sub * 4;
    atomicAdd(o + 0, val * xv.x);
    atomicAdd(o + 1, val * xv.y);
    atomicAdd(o + 2, val * xv.z);
    atomicAdd(o + 3, val * xv.w);
}

// ---------------- launch ----------------

extern "C" void kernel_launch(void* const* d_in, const int* in_sizes, int n_in,
                              void* d_out, int out_size, void* d_ws, size_t ws_size,
                              hipStream_t stream) {
    const float* x         = (const float*)d_in[0];
    const int*   edge_rows = (const int*)d_in[1];
    const int*   edge_cols = (const int*)d_in[2];
    const float* edge_vals = (const float*)d_in[3];
    float* out = (float*)d_out;

    // workspace layout (int elements from base):
    //   counts   @ 0          150000
    //   partials @ 150016     147
    //   cursor   @ 150208     150000
    //   recs     @ 300224     (uint2, 2.4M)  -> byte offset 1,200,896 (8B aligned)
    int* ws_i = (int*)d_ws;
    const size_t NEED = 300224u * 4u + (size_t)NREL * NEDGE * sizeof(uint2); // ~20.4 MB

    if (ws_size >= NEED) {
        int*   counts   = ws_i;
        int*   partials = ws_i + 150016;
        int*   cursor   = ws_i + 150208;
        uint2* recs     = (uint2*)(ws_i + 300224);

        zero_counts_kernel<<<(NBINS + 255) / 256, 256, 0, stream>>>(counts);
        count2_kernel<<<dim3(EDGE_BLOCKS, NREL), 256, 0, stream>>>(edge_rows, counts);
        scanA_kernel<<<SCAN_BLOCKS, 256, 0, stream>>>(counts, partials);
        scanB_kernel<<<1, 256, 0, stream>>>(partials);
        scanC_kernel<<<SCAN_BLOCKS, 256, 0, stream>>>(counts, partials, cursor);
        scatter2_kernel<<<dim3(EDGE_BLOCKS, NREL), 256, 0, stream>>>(
            edge_rows, edge_cols, edge_vals, cursor, recs);
        accum2_kernel<<<dim3(NRB, NREL), 512, 0, stream>>>(x, cursor, recs, out);
        copyx_kernel<<<(N_NODES * 16 + 255) / 256, 256, 0, stream>>>(
            (const float4*)x, (float4*)out);
    } else {
        // Fallback: global-atomic scatter (correct, slower)
        {
            int total = N_NODES * 64;
            init_out_kernel<<<(total + 255) / 256, 256, 0, stream>>>(
                (const float4*)x, (float4*)out);
        }
        {
            int threads_per_rel = NEDGE * 16;
            int blocks = (threads_per_rel + 255) / 256;
            dim3 grid(blocks, NREL);
            scatter_spmm_kernel<<<grid, 256, 0, stream>>>(
                x, edge_rows, edge_cols, edge_vals, out);
        }
    }
}

// Round 7
// 159.795 us; speedup vs baseline: 5.8491x; 2.6312x over previous
//
#include <hip/hip_runtime.h>

// Problem constants: N=50000, D=64, R=3, E=800000
#define N_NODES 50000
#define DFEAT   64
#define NREL    3
#define NEDGE   800000
#define OUT_COLS 256                 // (R+1)*D floats per output row
#define BROWS   128                  // rows per bucket
#define NBUCK   ((N_NODES + BROWS - 1) / BROWS)   // 391
#define TB      (NREL * NBUCK)       // 1173
#define SCAT_BLOCKS 200
#define SRTCAP  2560                 // LDS sorted-record capacity (mean 2046, sd~45)

// ---------------- bucketed + row-sorted register-accumulate path ----------------

__global__ void zero_counts_kernel(int* __restrict__ counts) {
    int i = blockIdx.x * 256 + threadIdx.x;
    if (i < TB) counts[i] = 0;
}

// grid (128, NREL), block 256. LDS histogram per block, flush with atomics.
__global__ void count_kernel(const int* __restrict__ rows, int* __restrict__ counts) {
    __shared__ int hist[NBUCK];
    int rel = blockIdx.y;
    int tid = threadIdx.x;
    for (int i = tid; i < NBUCK; i += 256) hist[i] = 0;
    __syncthreads();
    const int* rr = rows + rel * NEDGE;
    for (int e = blockIdx.x * 256 + tid; e < NEDGE; e += gridDim.x * 256)
        atomicAdd(&hist[rr[e] >> 7], 1);
    __syncthreads();
    for (int i = tid; i < NBUCK; i += 256)
        if (hist[i]) atomicAdd(&counts[rel * NBUCK + i], hist[i]);
}

// single block of 256. counts[TB] -> offsets[TB+1]; cursor = copy of offsets.
__global__ void scan_kernel(const int* __restrict__ counts,
                            int* __restrict__ offsets,
                            int* __restrict__ cursor) {
    __shared__ int part[256];
    const int PER = (TB + 255) / 256;   // 5
    int t = threadIdx.x;
    int base = t * PER;
    int loc[PER];
    int s = 0;
    for (int k = 0; k < PER; ++k) {
        int idx = base + k;
        int v = (idx < TB) ? counts[idx] : 0;
        loc[k] = s;
        s += v;
    }
    part[t] = s;
    __syncthreads();
    for (int off = 1; off < 256; off <<= 1) {
        int v = 0;
        if (t >= off) v = part[t - off];
        __syncthreads();
        if (t >= off) part[t] += v;
        __syncthreads();
    }
    int excl = (t == 0) ? 0 : part[t - 1];
    for (int k = 0; k < PER; ++k) {
        int idx = base + k;
        if (idx < TB) {
            int v = excl + loc[k];
            offsets[idx] = v;
            cursor[idx]  = v;
        }
    }
    if (t == 255) offsets[TB] = part[255];
}

// grid (SCAT_BLOCKS, NREL), block 256. Two-pass block reservation, then scatter
// packed records {(col<<7)|rowlocal, val_bits} into bucket-contiguous ws.
__global__ void scatter_kernel(const int* __restrict__ rows,
                               const int* __restrict__ cols,
                               const float* __restrict__ vals,
                               int* __restrict__ cursor,
                               uint2* __restrict__ recs) {
    __shared__ int hist[NBUCK];
    __shared__ int basei[NBUCK];
    int rel = blockIdx.y;
    int tid = threadIdx.x;
    for (int i = tid; i < NBUCK; i += 256) hist[i] = 0;
    __syncthreads();
    const int*   rr = rows + rel * NEDGE;
    const int*   cc = cols + rel * NEDGE;
    const float* vv = vals + rel * NEDGE;
    const int chunk = (NEDGE + gridDim.x - 1) / gridDim.x;
    int e0 = blockIdx.x * chunk;
    int e1 = min(e0 + chunk, NEDGE);
    for (int e = e0 + tid; e < e1; e += 256)
        atomicAdd(&hist[rr[e] >> 7], 1);
    __syncthreads();
    for (int i = tid; i < NBUCK; i += 256) {
        int c = hist[i];
        basei[i] = (c > 0) ? atomicAdd(&cursor[rel * NBUCK + i], c) : 0;
        hist[i] = 0;
    }
    __syncthreads();
    for (int e = e0 + tid; e < e1; e += 256) {
        int row = rr[e];
        int bk = row >> 7;
        int pos = basei[bk] + atomicAdd(&hist[bk], 1);
        recs[pos] = make_uint2(((unsigned)cc[e] << 7) | (unsigned)(row & 127),
                               __float_as_uint(vv[e]));
    }
}

// grid TB blocks, block 512 (8 waves). Counting-sort the bucket's records by
// LOCAL ROW into LDS (two passes over the block's contiguous global segment,
// ~2K LDS atomics per block), then wave w register-accumulates rows
// [16w, 16w+16): lane d holds out[row, rel*64+d] in a register (2 partial
// sums, unroll 4) and does one plain coalesced store per row. No LDS
// accumulator, no atomics in the hot loop. rel==0 blocks also copy
// x -> out[:,192:256] for their rows (fused copyx).
__global__ void accum3_kernel(const float* __restrict__ x,
                              const int* __restrict__ offsets,
                              const uint2* __restrict__ recs,
                              float* __restrict__ out) {
    __shared__ uint2 srt[SRTCAP];        // 20 KB
    __shared__ int bins[BROWS];
    __shared__ int rowoff[BROWS + 1];

    int b    = blockIdx.x;
    int rel  = b / NBUCK;
    int buck = b % NBUCK;
    int tid  = threadIdx.x;
    int lane = tid & 63, w = tid >> 6;
    int row0 = buck * BROWS;

    int start = offsets[b], end = offsets[b + 1];
    int total = end - start;

    if (total <= SRTCAP) {
        if (tid < BROWS) bins[tid] = 0;
        __syncthreads();
        // pass 1: per-row histogram
        for (int i = start + tid; i < end; i += 512)
            atomicAdd(&bins[recs[i].x & 127], 1);
        __syncthreads();
        // exclusive scan of 128 bins (serial on t0: ~128 iters, negligible)
        if (tid == 0) {
            int s = 0;
            rowoff[0] = 0;
            for (int k = 0; k < BROWS; ++k) {
                int v = bins[k];
                bins[k] = s;          // becomes scatter cursor
                s += v;
                rowoff[k + 1] = s;
            }
        }
        __syncthreads();
        // pass 2: scatter into row-sorted LDS copy (segment is L2-hot now)
        for (int i = start + tid; i < end; i += 512) {
            uint2 r = recs[i];
            int pos = atomicAdd(&bins[r.x & 127], 1);
            srt[pos] = r;
        }
        __syncthreads();

        // replay: wave w owns 16 consecutive local rows
        int rl0 = w * 16;
        for (int rl = rl0; rl < rl0 + 16; ++rl) {
            int row = row0 + rl;
            if (row >= N_NODES) break;
            float s0 = 0.f, s1 = 0.f;
            int j = rowoff[rl], e1 = rowoff[rl + 1];
            for (; j + 4 <= e1; j += 4) {
                uint2 a = srt[j];
                uint2 bb = srt[j + 1];
                uint2 c = srt[j + 2];
                uint2 d = srt[j + 3];
                float xa = x[((a.x  >> 7) << 6) + lane];
                float xb = x[((bb.x >> 7) << 6) + lane];
                float xc = x[((c.x  >> 7) << 6) + lane];
                float xd = x[((d.x  >> 7) << 6) + lane];
                s0 = fmaf(__uint_as_float(a.y),  xa, s0);
                s1 = fmaf(__uint_as_float(bb.y), xb, s1);
                s0 = fmaf(__uint_as_float(c.y),  xc, s0);
                s1 = fmaf(__uint_as_float(d.y),  xd, s1);
            }
            for (; j < e1; ++j) {
                uint2 a = srt[j];
                s0 = fmaf(__uint_as_float(a.y), x[((a.x >> 7) << 6) + lane], s0);
            }
            out[(long)row * OUT_COLS + rel * DFEAT + lane] = s0 + s1;
        }
    } else {
        // overflow slow path (statistically never): per-row scan of the
        // whole segment straight from global.
        int rl0 = w * 16;
        for (int rl = rl0; rl < rl0 + 16; ++rl) {
            int row = row0 + rl;
            if (row >= N_NODES) break;
            float s0 = 0.f;
            for (int j = start; j < end; ++j) {
                uint2 a = recs[j];
                if ((int)(a.x & 127) == rl)
                    s0 = fmaf(__uint_as_float(a.y), x[((a.x >> 7) << 6) + lane], s0);
            }
            out[(long)row * OUT_COLS + rel * DFEAT + lane] = s0;
        }
    }

    // fused copyx: rel 0 blocks copy x rows into out[:,192:256]
    if (rel == 0) {
        int rl0 = w * 16;
        for (int rl = rl0; rl < rl0 + 16; ++rl) {
            int row = row0 + rl;
            if (row >= N_NODES) break;
            out[(long)row * OUT_COLS + 192 + lane] = x[row * DFEAT + lane];
        }
    }
}

// ---------------- fallback path (no workspace) ----------------

__global__ void init_out_kernel(const float4* __restrict__ x4, float4* __restrict__ out4) {
    int j = blockIdx.x * blockDim.x + threadIdx.x;
    if (j >= N_NODES * 64) return;
    int row = j >> 6, c = j & 63;
    float4 v;
    if (c < 48) v = make_float4(0.f, 0.f, 0.f, 0.f);
    else        v = x4[row * 16 + (c - 48)];
    out4[j] = v;
}

__global__ void scatter_spmm_kernel(const float* __restrict__ x,
                                    const int* __restrict__ rows,
                                    const int* __restrict__ cols,
                                    const float* __restrict__ vals,
                                    float* __restrict__ out) {
    int idx = blockIdx.x * blockDim.x + threadIdx.x;
    int e = idx >> 4, sub = idx & 15;
    if (e >= NEDGE) return;
    int r = blockIdx.y;
    long base = (long)r * NEDGE + e;
    int row = rows[base], col = cols[base];
    float val = vals[base];
    const float4 xv = *reinterpret_cast<const float4*>(x + (long)col * DFEAT + sub * 4);
    float* o = out + (long)row * OUT_COLS + r * DFEAT + sub * 4;
    atomicAdd(o + 0, val * xv.x);
    atomicAdd(o + 1, val * xv.y);
    atomicAdd(o + 2, val * xv.z);
    atomicAdd(o + 3, val * xv.w);
}

// ---------------- launch ----------------

extern "C" void kernel_launch(void* const* d_in, const int* in_sizes, int n_in,
                              void* d_out, int out_size, void* d_ws, size_t ws_size,
                              hipStream_t stream) {
    const float* x         = (const float*)d_in[0];
    const int*   edge_rows = (const int*)d_in[1];
    const int*   edge_cols = (const int*)d_in[2];
    const float* edge_vals = (const float*)d_in[3];
    float* out = (float*)d_out;

    const size_t REC_OFF = 32768;
    const size_t NEED = REC_OFF + (size_t)NREL * NEDGE * sizeof(uint2);  // ~19.2 MB

    if (ws_size >= NEED) {
        int*   counts  = (int*)d_ws;            // TB ints
        int*   offsets = counts + TB;           // TB+1 ints
        int*   cursor  = offsets + TB + 1;      // TB ints  (< 32 KB total)
        uint2* recs    = (uint2*)((char*)d_ws + REC_OFF);

        zero_counts_kernel<<<(TB + 255) / 256, 256, 0, stream>>>(counts);
        count_kernel<<<dim3(128, NREL), 256, 0, stream>>>(edge_rows, counts);
        scan_kernel<<<1, 256, 0, stream>>>(counts, offsets, cursor);
        scatter_kernel<<<dim3(SCAT_BLOCKS, NREL), 256, 0, stream>>>(
            edge_rows, edge_cols, edge_vals, cursor, recs);
        accum3_kernel<<<TB, 512, 0, stream>>>(x, offsets, recs, out);
    } else {
        // Fallback: global-atomic scatter (correct, slower)
        {
            int total = N_NODES * 64;
            init_out_kernel<<<(total + 255) / 256, 256, 0, stream>>>(
                (const float4*)x, (float4*)out);
        }
        {
            int threads_per_rel = NEDGE * 16;
            int blocks = (threads_per_rel + 255) / 256;
            dim3 grid(blocks, NREL);
            scatter_spmm_kernel<<<grid, 256, 0, stream>>>(
                x, edge_rows, edge_cols, edge_vals, out);
        }
    }
}